// Round 3
// baseline (440.537 us; speedup 1.0000x reference)
//
#include <hip/hip_runtime.h>

// GCN: N=50000 nodes, E=800000 edges, 64 -> 96 -> 96 -> 32, fp32.
// R2: (a) bucketed 2-pass CSR build (LDS counting sort per 98-node bucket,
//     sequential u16 srcs writes) replaces hist+scan+fill_csr (52MB write
//     thrash, 50K-way atomics). (b) layer-1 aggregates x (64ch) before GEMM
//     since row-scale+adjacency-sum commute with the weight multiply.
// Pipeline:
//   pass1/pass2: CSR(srcs,row_start,counts), dinv=rsqrt(1+indeg), u=dinv*x
//   B1 = gather64(u);  g1 = dinv*relu((dinv*B1)@W1 + b1)     [GEMM1 fused]
//   B2 = gather96(g1); h2 = relu(dinv*(B2@W2) + b2)          [GEMM2 fused]
//   out = h2 @ Wfc + bfc                                     [FC fused]

constexpr int NN = 50000;
constexpr int NE = 800000;
constexpr int NB = 512;    // buckets
constexpr int NPB = 98;    // nodes per bucket (512*98 = 50176 >= NN)
constexpr int BCAP = 2048; // max edges per bucket (mean 1563, +12 sigma safe)

// ---------------- CSR pass 1: bucket edges by dst range ----------------
__global__ __launch_bounds__(256) void csr_pass1(const int* __restrict__ ei,
                                                 int* __restrict__ bcnt,
                                                 unsigned* __restrict__ bbuf) {
  int e = blockIdx.x * 256 + threadIdx.x;
  if (e >= NE) return;
  unsigned src = (unsigned)ei[e];
  unsigned dst = (unsigned)ei[NE + e];
  unsigned b = dst / NPB;
  unsigned dl = dst - b * NPB;
  int p = atomicAdd(&bcnt[b], 1);
  if (p < BCAP) bbuf[b * BCAP + p] = (dl << 16) | src;
}

// ------- CSR pass 2: per-bucket LDS counting sort + node outputs -------
__global__ __launch_bounds__(256) void csr_pass2(
    const int* __restrict__ bcnt, const unsigned* __restrict__ bbuf,
    const float* __restrict__ x, int* __restrict__ row_start,
    int* __restrict__ counts, float* __restrict__ dinv, float* __restrict__ u,
    unsigned short* __restrict__ srcs) {
  __shared__ int s_red[256];
  __shared__ int s_cnt[128];   // per-node count, later cursor
  __shared__ int s_scan[128];  // inclusive scan
  __shared__ float s_dinv[128];
  __shared__ unsigned short s_sorted[BCAP];
  const int b = blockIdx.x, t = threadIdx.x;
  const int cnt_b = min(bcnt[b], BCAP);

  // exclusive prefix over bucket counts -> global base of this bucket
  int acc = 0;
  for (int j = t; j < b; j += 256) acc += min(bcnt[j], BCAP);
  s_red[t] = acc;
  __syncthreads();
  for (int off = 128; off > 0; off >>= 1) {
    if (t < off) s_red[t] += s_red[t + off];
    __syncthreads();
  }
  const int base = s_red[0];

  if (t < 128) s_cnt[t] = 0;
  __syncthreads();
  for (int i = t; i < cnt_b; i += 256)
    atomicAdd(&s_cnt[bbuf[b * BCAP + i] >> 16], 1);
  __syncthreads();

  // inclusive Hillis-Steele scan over 128 node counters
  if (t < 128) s_scan[t] = s_cnt[t];
  __syncthreads();
  for (int off = 1; off < 128; off <<= 1) {
    int v = 0;
    if (t < 128 && t >= off) v = s_scan[t - off];
    __syncthreads();
    if (t < 128) s_scan[t] += v;
    __syncthreads();
  }

  const int node = b * NPB + t;
  if (t < NPB && node < NN) {
    int c = s_cnt[t];
    int ex = s_scan[t] - c;  // exclusive
    row_start[node] = base + ex;
    counts[node] = c;
    float di = rsqrtf(1.0f + (float)c);
    dinv[node] = di;
    s_dinv[t] = di;
  }
  __syncthreads();
  if (t < 128) s_cnt[t] = s_scan[t] - ((t < 128) ? (s_scan[t] - s_cnt[t]) : 0);
  // ^ set cursor = exclusive prefix:
  if (t < 128) s_cnt[t] = s_scan[t];  // placeholder fixed below
  __syncthreads();
  // (recompute exclusive cleanly to avoid the aliasing above)
  if (t < 128) s_cnt[t] = (t == 0) ? 0 : s_scan[t - 1];
  __syncthreads();

  // scatter into LDS in dst-sorted order
  for (int i = t; i < cnt_b; i += 256) {
    unsigned w = bbuf[b * BCAP + i];
    int pos = atomicAdd(&s_cnt[w >> 16], 1);
    s_sorted[pos] = (unsigned short)(w & 0xFFFFu);
  }
  __syncthreads();
  // sequential global write of sorted srcs (u16)
  for (int i = t; i < cnt_b; i += 256) srcs[base + i] = s_sorted[i];

  // fused: u = dinv * x for this bucket's nodes (64 ch = 16 quads/node)
  const float4* x4 = (const float4*)x;
  float4* u4 = (float4*)u;
  for (int i = t; i < NPB * 16; i += 256) {
    int nl = i >> 4, q = i & 15;
    int n = b * NPB + nl;
    if (n < NN) {
      float di = s_dinv[nl];
      float4 v = x4[(size_t)n * 16 + q];
      v.x *= di; v.y *= di; v.z *= di; v.w *= di;
      u4[(size_t)n * 16 + q] = v;
    }
  }
}

// ------- gather: B[n] = A[n] + sum_{s in adj(n)} A[s], C channels -------
template <int C>
__global__ void gather(const int* __restrict__ row_start,
                       const int* __restrict__ counts,
                       const unsigned short* __restrict__ srcs,
                       const float* __restrict__ A, float* __restrict__ B) {
  constexpr int QP = C / 4;
  int gid = blockIdx.x * blockDim.x + threadIdx.x;
  if (gid >= NN * QP) return;
  int n, q;
  if constexpr ((QP & (QP - 1)) == 0) {
    n = gid >> 4;  // QP == 16
    q = gid & 15;
  } else {
    n = gid / QP;
    q = gid - n * QP;
  }
  const float4* A4 = (const float4*)A;
  float4 acc = A4[(size_t)n * QP + q];  // self-loop term
  int s0 = row_start[n];
  int cnt = counts[n];
  for (int p = 0; p < cnt; ++p) {
    int s = (int)srcs[s0 + p];
    float4 v = A4[(size_t)s * QP + q];
    acc.x += v.x; acc.y += v.y; acc.z += v.z; acc.w += v.w;
  }
  ((float4*)B)[(size_t)n * QP + q] = acc;
}

// ---------------- GEMM with fused transforms ----------------
// IMODE: 0 plain input, 1 input row-scaled by dinv
// EMODE: 1: out = dinv*relu(acc+bin)  2: out = relu(dinv*acc+bin)  3: acc+bin
template <int K, int M, int BN, int NPT, int CPT, int IMODE, int EMODE,
          int BLOCK>
__global__ __launch_bounds__(BLOCK) void gcn_gemm(
    const float* __restrict__ X, const float* __restrict__ W,
    const float* __restrict__ bin, const float* __restrict__ dinv,
    float* __restrict__ out) {
  constexpr int TCX = M / CPT;
  static_assert((BN / NPT) * TCX == BLOCK, "thread layout mismatch");
  __shared__ float sW[K * M];
  __shared__ float sX[BN][K + 1];

  const int tid = threadIdx.x;
  const int nb = blockIdx.x * BN;

  {
    const float4* W4 = (const float4*)W;
    float4* sW4 = (float4*)sW;
    #pragma unroll
    for (int i = tid; i < K * M / 4; i += BLOCK) sW4[i] = W4[i];
  }
  {
    constexpr int KQ = K / 4;
    for (int i = tid; i < BN * KQ; i += BLOCK) {
      int n = i / KQ, kq = i - n * KQ;
      int gn = nb + n;
      float4 v = {0.f, 0.f, 0.f, 0.f};
      if (gn < NN) {
        v = *(const float4*)(X + (size_t)gn * K + 4 * kq);
        if (IMODE == 1) {
          float di = dinv[gn];
          v.x *= di; v.y *= di; v.z *= di; v.w *= di;
        }
      }
      sX[n][4 * kq + 0] = v.x;
      sX[n][4 * kq + 1] = v.y;
      sX[n][4 * kq + 2] = v.z;
      sX[n][4 * kq + 3] = v.w;
    }
  }
  __syncthreads();

  const int cx = tid % TCX, ry = tid / TCX;
  const int c0 = cx * CPT, r0 = ry * NPT;
  float acc[NPT][CPT] = {};
  #pragma unroll 4
  for (int k = 0; k < K; ++k) {
    float wv[CPT], xv[NPT];
    #pragma unroll
    for (int j = 0; j < CPT; ++j) wv[j] = sW[k * M + c0 + j];
    #pragma unroll
    for (int i = 0; i < NPT; ++i) xv[i] = sX[r0 + i][k];
    #pragma unroll
    for (int i = 0; i < NPT; ++i)
      #pragma unroll
      for (int j = 0; j < CPT; ++j) acc[i][j] = fmaf(xv[i], wv[j], acc[i][j]);
  }

  #pragma unroll
  for (int i = 0; i < NPT; ++i) {
    int gn = nb + r0 + i;
    if (gn >= NN) continue;
    float di = (EMODE != 3) ? dinv[gn] : 0.f;
    #pragma unroll
    for (int j = 0; j < CPT; ++j) {
      float v;
      if (EMODE == 1)      v = di * fmaxf(acc[i][j] + bin[c0 + j], 0.f);
      else if (EMODE == 2) v = fmaxf(fmaf(di, acc[i][j], bin[c0 + j]), 0.f);
      else                 v = acc[i][j] + bin[c0 + j];
      out[(size_t)gn * M + c0 + j] = v;
    }
  }
}

extern "C" void kernel_launch(void* const* d_in, const int* in_sizes, int n_in,
                              void* d_out, int out_size, void* d_ws,
                              size_t ws_size, hipStream_t stream) {
  const float* x   = (const float*)d_in[0];
  const int*   ei  = (const int*)d_in[1];
  const float* W1  = (const float*)d_in[2];
  const float* b1  = (const float*)d_in[3];
  const float* W2  = (const float*)d_in[4];
  const float* b2  = (const float*)d_in[5];
  const float* Wfc = (const float*)d_in[6];
  const float* bfc = (const float*)d_in[7];
  float* out = (float*)d_out;

  // workspace layout
  float* dinv = (float*)d_ws;                       // [50048]
  float* P0 = dinv + 50048;                         // [N*96] ping
  float* P1 = P0 + (size_t)NN * 96;                 // [N*96] pong
  int* row_start = (int*)(P1 + (size_t)NN * 96);    // [50048]
  int* counts = row_start + 50048;                  // [50048]
  int* bcnt = counts + 50048;                       // [512]
  unsigned short* srcs = (unsigned short*)(bcnt + 512);  // [NE] u16
  unsigned* bbuf = (unsigned*)P1;  // pass1/2 scratch aliases P1 (4MB < 19.2MB)

  hipMemsetAsync(bcnt, 0, NB * sizeof(int), stream);
  csr_pass1<<<(NE + 255) / 256, 256, 0, stream>>>(ei, bcnt, bbuf);
  csr_pass2<<<NB, 256, 0, stream>>>(bcnt, bbuf, x, row_start, counts, dinv,
                                    /*u=*/P0, srcs);

  // B1 = gather64(u): P0 -> P1
  gather<64><<<(NN * 16 + 255) / 256, 256, 0, stream>>>(row_start, counts,
                                                        srcs, P0, P1);
  // g1 = dinv*relu((dinv*B1)@W1 + b1): P1 -> P0
  gcn_gemm<64, 96, 64, 8, 6, 1, 1, 128>
      <<<(NN + 63) / 64, 128, 0, stream>>>(P1, W1, b1, dinv, P0);
  // B2 = gather96(g1): P0 -> P1
  gather<96><<<(NN * 24 + 255) / 256, 256, 0, stream>>>(row_start, counts,
                                                        srcs, P0, P1);
  // h2 = relu(dinv*(B2@W2) + b2): P1 -> P0
  gcn_gemm<96, 96, 64, 8, 6, 0, 2, 128>
      <<<(NN + 63) / 64, 128, 0, stream>>>(P1, W2, b2, dinv, P0);
  // out = h2 @ Wfc + bfc
  gcn_gemm<96, 32, 128, 8, 4, 0, 3, 128>
      <<<(NN + 127) / 128, 128, 0, stream>>>(P0, Wfc, bfc, dinv, out);
}

// Round 4
// 188.787 us; speedup vs baseline: 2.3335x; 2.3335x over previous
//
#include <hip/hip_runtime.h>

// GCN: N=50000 nodes, E=800000 edges, 64 -> 96 -> 96 -> 32, fp32.
// R3: fix R2's csr_pass1 atomic-contention disaster (244us: 800K atomics on
// 512 global counters). New pass1: per-block LDS counting sort of 8192 edges
// over 512 buckets + ONE global atomicAdd per (block,bucket) bulk reservation
// (50K atomics total), run-coalesced output writes. Also: 4-way edge unroll
// in gather (latency-bound: VALUBusy was 6.7%).
// Pipeline:
//   pass1: bucket edges by dst/98, packed (b:9|dl:7|src:16)
//   pass2: per-bucket LDS sort -> CSR(srcs u16, row_start, counts),
//          dinv=rsqrt(1+indeg), u=dinv*x (fused)
//   B1 = gather64(u);  g1 = dinv*relu((dinv*B1)@W1 + b1)   [GEMM1 fused]
//   B2 = gather96(g1); h2 = relu(dinv*(B2@W2) + b2)        [GEMM2 fused]
//   out = h2 @ Wfc + bfc                                   [FC fused]

constexpr int NN = 50000;
constexpr int NE = 800000;
constexpr int NB = 512;     // buckets
constexpr int NPB = 98;     // nodes per bucket (512*98 = 50176 >= NN)
constexpr int BCAP = 2048;  // max edges per bucket (mean 1563; R2 verified fit)
constexpr int EPB = 8192;   // edges per pass1 block
constexpr int P1B = 1024;   // pass1 block size
constexpr int NP1 = (NE + EPB - 1) / EPB;  // 98 blocks

// ---------------- CSR pass 1: block-local sort + bulk reservation ----------
__global__ __launch_bounds__(P1B) void csr_pass1(const int* __restrict__ ei,
                                                 int* __restrict__ bcnt,
                                                 unsigned* __restrict__ bbuf) {
  __shared__ unsigned sorted[EPB];  // 32KB
  __shared__ int hist[NB];
  __shared__ int lofs[NB];   // local exclusive prefix
  __shared__ int cursor[NB];
  __shared__ int gbase[NB];  // global reserved base within bucket
  const int t = threadIdx.x;
  const int e0 = blockIdx.x * EPB;
  const int ecnt = min(EPB, NE - e0);

  for (int i = t; i < NB; i += P1B) hist[i] = 0;
  __syncthreads();

  // phase A: histogram
  for (int i = t; i < ecnt; i += P1B) {
    unsigned dst = (unsigned)ei[NE + e0 + i];
    atomicAdd(&hist[dst / NPB], 1);
  }
  __syncthreads();

  // phase B: scan 512 (Hillis-Steele on first 512 threads) + reserve
  if (t < NB) lofs[t] = hist[t];
  __syncthreads();
  for (int off = 1; off < NB; off <<= 1) {
    int v = 0;
    if (t < NB && t >= off) v = lofs[t - off];
    __syncthreads();
    if (t < NB) lofs[t] += v;
    __syncthreads();
  }
  if (t < NB) {
    int ex = lofs[t] - hist[t];  // exclusive
    lofs[t] = ex;
    cursor[t] = ex;
    gbase[t] = atomicAdd(&bcnt[t], hist[t]);
  }
  __syncthreads();

  // phase C: LDS scatter sorted by bucket (re-read edges; regs would spill)
  for (int i = t; i < ecnt; i += P1B) {
    unsigned src = (unsigned)ei[e0 + i];
    unsigned dst = (unsigned)ei[NE + e0 + i];
    unsigned b = dst / NPB;
    unsigned dl = dst - b * NPB;
    int pos = atomicAdd(&cursor[b], 1);
    sorted[pos] = (b << 23) | (dl << 16) | src;
  }
  __syncthreads();

  // phase D: run-coalesced global writes
  for (int i = t; i < ecnt; i += P1B) {
    unsigned pw = sorted[i];
    unsigned b = pw >> 23;
    int off_in_b = gbase[b] + (i - lofs[b]);
    if (off_in_b < BCAP)
      bbuf[b * BCAP + off_in_b] = pw & 0x007FFFFFu;  // (dl<<16)|src
  }
}

// ------- CSR pass 2: per-bucket LDS counting sort + node outputs -------
__global__ __launch_bounds__(256) void csr_pass2(
    const int* __restrict__ bcnt, const unsigned* __restrict__ bbuf,
    const float* __restrict__ x, int* __restrict__ row_start,
    int* __restrict__ counts, float* __restrict__ dinv, float* __restrict__ u,
    unsigned short* __restrict__ srcs) {
  __shared__ int s_red[256];
  __shared__ int s_cnt[128];
  __shared__ int s_scan[128];
  __shared__ int s_cur[128];
  __shared__ float s_dinv[128];
  __shared__ unsigned short s_sorted[BCAP];
  const int b = blockIdx.x, t = threadIdx.x;
  const int cnt_b = min(bcnt[b], BCAP);

  // global base = sum of bucket counts before b
  int acc = 0;
  for (int j = t; j < b; j += 256) acc += min(bcnt[j], BCAP);
  s_red[t] = acc;
  __syncthreads();
  for (int off = 128; off > 0; off >>= 1) {
    if (t < off) s_red[t] += s_red[t + off];
    __syncthreads();
  }
  const int base = s_red[0];

  if (t < 128) s_cnt[t] = 0;
  __syncthreads();
  for (int i = t; i < cnt_b; i += 256)
    atomicAdd(&s_cnt[bbuf[b * BCAP + i] >> 16], 1);
  __syncthreads();

  if (t < 128) s_scan[t] = s_cnt[t];
  __syncthreads();
  for (int off = 1; off < 128; off <<= 1) {
    int v = 0;
    if (t < 128 && t >= off) v = s_scan[t - off];
    __syncthreads();
    if (t < 128) s_scan[t] += v;
    __syncthreads();
  }
  if (t < 128) s_cur[t] = s_scan[t] - s_cnt[t];  // exclusive

  const int node = b * NPB + t;
  if (t < NPB && node < NN) {
    int c = s_cnt[t];
    row_start[node] = base + s_scan[t] - c;
    counts[node] = c;
    float di = rsqrtf(1.0f + (float)c);
    dinv[node] = di;
    s_dinv[t] = di;
  }
  __syncthreads();

  for (int i = t; i < cnt_b; i += 256) {
    unsigned w = bbuf[b * BCAP + i];
    int pos = atomicAdd(&s_cur[w >> 16], 1);
    s_sorted[pos] = (unsigned short)(w & 0xFFFFu);
  }
  __syncthreads();
  for (int i = t; i < cnt_b; i += 256) srcs[base + i] = s_sorted[i];

  // fused: u = dinv * x (64 ch = 16 quads/node)
  const float4* x4 = (const float4*)x;
  float4* u4 = (float4*)u;
  for (int i = t; i < NPB * 16; i += 256) {
    int nl = i >> 4, q = i & 15;
    int n = b * NPB + nl;
    if (n < NN) {
      float di = s_dinv[nl];
      float4 v = x4[(size_t)n * 16 + q];
      v.x *= di; v.y *= di; v.z *= di; v.w *= di;
      u4[(size_t)n * 16 + q] = v;
    }
  }
}

// ------- gather: B[n] = A[n] + sum_{s in adj(n)} A[s], C channels -------
template <int C>
__global__ __launch_bounds__(256) void gather(
    const int* __restrict__ row_start, const int* __restrict__ counts,
    const unsigned short* __restrict__ srcs, const float* __restrict__ A,
    float* __restrict__ B) {
  constexpr int QP = C / 4;
  int gid = blockIdx.x * blockDim.x + threadIdx.x;
  if (gid >= NN * QP) return;
  int n, q;
  if constexpr ((QP & (QP - 1)) == 0) {
    n = gid >> 4;  // QP == 16
    q = gid & 15;
  } else {
    n = gid / QP;
    q = gid - n * QP;
  }
  const float4* A4 = (const float4*)A + q;
  float4 acc = A4[(size_t)n * QP];  // self-loop term
  float4 acc2 = {0.f, 0.f, 0.f, 0.f};
  const int s0 = row_start[n];
  const int cnt = counts[n];
  int p = 0;
  for (; p + 4 <= cnt; p += 4) {  // 4 independent loads in flight
    int sa = srcs[s0 + p + 0];
    int sb = srcs[s0 + p + 1];
    int sc = srcs[s0 + p + 2];
    int sd = srcs[s0 + p + 3];
    float4 va = A4[(size_t)sa * QP];
    float4 vb = A4[(size_t)sb * QP];
    float4 vc = A4[(size_t)sc * QP];
    float4 vd = A4[(size_t)sd * QP];
    acc.x += va.x + vb.x; acc.y += va.y + vb.y;
    acc.z += va.z + vb.z; acc.w += va.w + vb.w;
    acc2.x += vc.x + vd.x; acc2.y += vc.y + vd.y;
    acc2.z += vc.z + vd.z; acc2.w += vc.w + vd.w;
  }
  for (; p < cnt; ++p) {
    int s = srcs[s0 + p];
    float4 v = A4[(size_t)s * QP];
    acc.x += v.x; acc.y += v.y; acc.z += v.z; acc.w += v.w;
  }
  acc.x += acc2.x; acc.y += acc2.y; acc.z += acc2.z; acc.w += acc2.w;
  ((float4*)B + q)[(size_t)n * QP] = acc;
}

// ---------------- GEMM with fused transforms ----------------
// IMODE: 0 plain input, 1 input row-scaled by dinv
// EMODE: 1: out = dinv*relu(acc+bin)  2: out = relu(dinv*acc+bin)  3: acc+bin
template <int K, int M, int BN, int NPT, int CPT, int IMODE, int EMODE,
          int BLOCK>
__global__ __launch_bounds__(BLOCK) void gcn_gemm(
    const float* __restrict__ X, const float* __restrict__ W,
    const float* __restrict__ bin, const float* __restrict__ dinv,
    float* __restrict__ out) {
  constexpr int TCX = M / CPT;
  static_assert((BN / NPT) * TCX == BLOCK, "thread layout mismatch");
  __shared__ float sW[K * M];
  __shared__ float sX[BN][K + 1];

  const int tid = threadIdx.x;
  const int nb = blockIdx.x * BN;

  {
    const float4* W4 = (const float4*)W;
    float4* sW4 = (float4*)sW;
    #pragma unroll
    for (int i = tid; i < K * M / 4; i += BLOCK) sW4[i] = W4[i];
  }
  {
    constexpr int KQ = K / 4;
    for (int i = tid; i < BN * KQ; i += BLOCK) {
      int n = i / KQ, kq = i - n * KQ;
      int gn = nb + n;
      float4 v = {0.f, 0.f, 0.f, 0.f};
      if (gn < NN) {
        v = *(const float4*)(X + (size_t)gn * K + 4 * kq);
        if (IMODE == 1) {
          float di = dinv[gn];
          v.x *= di; v.y *= di; v.z *= di; v.w *= di;
        }
      }
      sX[n][4 * kq + 0] = v.x;
      sX[n][4 * kq + 1] = v.y;
      sX[n][4 * kq + 2] = v.z;
      sX[n][4 * kq + 3] = v.w;
    }
  }
  __syncthreads();

  const int cx = tid % TCX, ry = tid / TCX;
  const int c0 = cx * CPT, r0 = ry * NPT;
  float acc[NPT][CPT] = {};
  #pragma unroll 4
  for (int k = 0; k < K; ++k) {
    float wv[CPT], xv[NPT];
    #pragma unroll
    for (int j = 0; j < CPT; ++j) wv[j] = sW[k * M + c0 + j];
    #pragma unroll
    for (int i = 0; i < NPT; ++i) xv[i] = sX[r0 + i][k];
    #pragma unroll
    for (int i = 0; i < NPT; ++i)
      #pragma unroll
      for (int j = 0; j < CPT; ++j) acc[i][j] = fmaf(xv[i], wv[j], acc[i][j]);
  }

  #pragma unroll
  for (int i = 0; i < NPT; ++i) {
    int gn = nb + r0 + i;
    if (gn >= NN) continue;
    float di = (EMODE != 3) ? dinv[gn] : 0.f;
    #pragma unroll
    for (int j = 0; j < CPT; ++j) {
      float v;
      if (EMODE == 1)      v = di * fmaxf(acc[i][j] + bin[c0 + j], 0.f);
      else if (EMODE == 2) v = fmaxf(fmaf(di, acc[i][j], bin[c0 + j]), 0.f);
      else                 v = acc[i][j] + bin[c0 + j];
      out[(size_t)gn * M + c0 + j] = v;
    }
  }
}

extern "C" void kernel_launch(void* const* d_in, const int* in_sizes, int n_in,
                              void* d_out, int out_size, void* d_ws,
                              size_t ws_size, hipStream_t stream) {
  const float* x   = (const float*)d_in[0];
  const int*   ei  = (const int*)d_in[1];
  const float* W1  = (const float*)d_in[2];
  const float* b1  = (const float*)d_in[3];
  const float* W2  = (const float*)d_in[4];
  const float* b2  = (const float*)d_in[5];
  const float* Wfc = (const float*)d_in[6];
  const float* bfc = (const float*)d_in[7];
  float* out = (float*)d_out;

  // workspace layout
  float* dinv = (float*)d_ws;                       // [50048]
  float* P0 = dinv + 50048;                         // [N*96] ping
  float* P1 = P0 + (size_t)NN * 96;                 // [N*96] pong
  int* row_start = (int*)(P1 + (size_t)NN * 96);    // [50048]
  int* counts = row_start + 50048;                  // [50048]
  int* bcnt = counts + 50048;                       // [512]
  unsigned short* srcs = (unsigned short*)(bcnt + 512);  // [NE] u16
  unsigned* bbuf = (unsigned*)P1;  // pass1/2 scratch aliases P1 (4MB < 19.2MB)

  hipMemsetAsync(bcnt, 0, NB * sizeof(int), stream);
  csr_pass1<<<NP1, P1B, 0, stream>>>(ei, bcnt, bbuf);
  csr_pass2<<<NB, 256, 0, stream>>>(bcnt, bbuf, x, row_start, counts, dinv,
                                    /*u=*/P0, srcs);

  // B1 = gather64(u): P0 -> P1
  gather<64><<<(NN * 16 + 255) / 256, 256, 0, stream>>>(row_start, counts,
                                                        srcs, P0, P1);
  // g1 = dinv*relu((dinv*B1)@W1 + b1): P1 -> P0
  gcn_gemm<64, 96, 64, 8, 6, 1, 1, 128>
      <<<(NN + 63) / 64, 128, 0, stream>>>(P1, W1, b1, dinv, P0);
  // B2 = gather96(g1): P0 -> P1
  gather<96><<<(NN * 24 + 255) / 256, 256, 0, stream>>>(row_start, counts,
                                                        srcs, P0, P1);
  // h2 = relu(dinv*(B2@W2) + b2): P1 -> P0
  gcn_gemm<96, 96, 64, 8, 6, 0, 2, 128>
      <<<(NN + 63) / 64, 128, 0, stream>>>(P1, W2, b2, dinv, P0);
  // out = h2 @ Wfc + bfc
  gcn_gemm<96, 32, 128, 8, 4, 0, 3, 128>
      <<<(NN + 127) / 128, 128, 0, stream>>>(P0, Wfc, bfc, dinv, out);
}